// Round 10
// baseline (484.623 us; speedup 1.0000x reference)
//
#include <hip/hip_runtime.h>
#include <hip/hip_bf16.h>

typedef unsigned short u16;
typedef _Float16 f16x8 __attribute__((ext_vector_type(8)));
typedef float f32x4 __attribute__((ext_vector_type(4)));

#if __has_builtin(__builtin_amdgcn_exp2f)
#define EXP2F(x) __builtin_amdgcn_exp2f(x)
#else
#define EXP2F(x) exp2f(x)
#endif
#define LOG2E 1.4426950408889634f

__device__ __forceinline__ f32x4 mfma16h(f16x8 a, f16x8 b, f32x4 c) {
  return __builtin_amdgcn_mfma_f32_16x16x32_f16(a, b, c, 0, 0, 0);
}
__device__ __forceinline__ unsigned pk2h(float a, float b) {
  union { _Float16 h[2]; unsigned u; } x;
  x.h[0] = (_Float16)a; x.h[1] = (_Float16)b;
  return x.u;
}
__device__ __forceinline__ u16 h1(float a) {
  union { _Float16 h; u16 u; } x; x.h = (_Float16)a; return x.u;
}
__device__ __forceinline__ float h2f(u16 a) {
  union { u16 u; _Float16 h; } x; x.u = a; return (float)x.h;
}

typedef __attribute__((address_space(1))) const unsigned int gas_u32;
typedef __attribute__((address_space(3))) unsigned int las_u32;
__device__ __forceinline__ void gl_lds16(const u16* g, u16* l) {
  __builtin_amdgcn_global_load_lds((gas_u32*)g, (las_u32*)l, 16, 0, 0);
}

// ---------------- cast fp32 -> f16, 8 elems/thread ----------------
__global__ __launch_bounds__(256) void cast_f16_k(const float* __restrict__ src,
                                                  u16* __restrict__ dst, int n8) {
  int i = blockIdx.x * 256 + threadIdx.x;
  if (i >= n8) return;
  const float4* s4 = (const float4*)src;
  float4 a = s4[i * 2], b = s4[i * 2 + 1];
  uint4 o;
  o.x = pk2h(a.x, a.y); o.y = pk2h(a.z, a.w);
  o.z = pk2h(b.x, b.y); o.w = pk2h(b.z, b.w);
  ((uint4*)dst)[i] = o;
}

// =================================================================
// 8-phase GEMM (round-9 proven sync structure, unchanged):
// BM=BN=256, BK=64, 8 waves (2Mx4N), acc 8x4, quarter-granularity staging.
//   ph0: read a0,b0 | ph1: read b1, stage A q0,q2(+2) | ph2: read a1, stage
//   B q0..q3(+2) | ph3: regs only, stage A q1,q3(+2); vmcnt(8) at ph3/ph7.
// Round-10 deltas (perf only, no sync change):
//   - removed post-MFMA sched_barrier(0) (m141: order-pinning hurts; WAR
//     ledger only needs the PRE-MFMA lgkmcnt(0), which is kept)
//   - T1 XCD-aware bijective swizzle of (bx,by) per z-slice (m204 formula)
//   EPI=0: D0 f16 = acc/32   EPI=1: Df f32 = acc
//   EPI=2: QKV scatter (Q,K row-major; V -> Vt[b][d][s])
// =================================================================
template <int K_, int EPI>
__global__ __launch_bounds__(512, 2) void gemm8p(
    const u16* __restrict__ A, const u16* __restrict__ B,
    const float* __restrict__ bias, u16* __restrict__ D0, u16* __restrict__ D1,
    u16* __restrict__ D2, float* __restrict__ Df, const int ldc,
    const size_t strA, const size_t strB, const size_t strC) {
  constexpr int NT = K_ / 64;
  static_assert(NT >= 4 && (NT % 2) == 0, "need even NT >= 4");
  __shared__ __align__(16) u16 As[2][2][128 * 64];   // [dbuf][M-half]
  __shared__ __align__(16) u16 Bs[2][2][128 * 64];   // [dbuf][N-half]

  const int tid = threadIdx.x, lane = tid & 63, wid = tid >> 6;
  const int l15 = lane & 15, lhi = lane >> 4;

  // T1: XCD-aware bijective block swizzle (m204) within each z-slice
  const int gx = gridDim.x;
  const int nwg = gx * gridDim.y;
  int bid = blockIdx.y * gx + blockIdx.x;
  {
    const int q = nwg >> 3, r = nwg & 7;
    const int x = bid & 7, o = bid >> 3;
    bid = (x < r ? x * (q + 1) : r * (q + 1) + (x - r) * q) + o;
  }
  const int m0 = (bid % gx) * 256, n0 = (bid / gx) * 256;

  const int wm = wid >> 2, wn = wid & 3;
  const u16* Ag = A + (size_t)blockIdx.z * strA;
  const u16* Bg = B + (size_t)blockIdx.z * strB;

  const int srow8 = lane >> 3;              // LDS row & 7 for this lane's 16B
  const int sblk = (lane & 7) ^ srow8;      // source block XOR (T2 both-sides)

// one 64-row quarter: 1 global_load_lds per wave (8 rows/wave)
#define STAGE_Q(BUF, G, GROW0, ST)                                        \
  gl_lds16((G) + (size_t)((GROW0) + wid * 8 + srow8) * K_ +               \
               (ST) * 64 + sblk * 8,                                      \
           (BUF) + (wid * 8) * 64)

#define BAR()                                                             \
  asm volatile("" ::: "memory");                                          \
  __builtin_amdgcn_s_barrier();                                           \
  asm volatile("" ::: "memory")

#define LGKM0()                                                           \
  asm volatile("s_waitcnt lgkmcnt(0)" ::: "memory");                      \
  __builtin_amdgcn_sched_barrier(0)

#define VMC8() asm volatile("s_waitcnt vmcnt(8)" ::: "memory")
#define VMC0() asm volatile("s_waitcnt vmcnt(0)" ::: "memory")

#define RD_A(DST, PB, MH)                                                 \
  _Pragma("unroll") for (int mf = 0; mf < 4; ++mf)                        \
  _Pragma("unroll") for (int ks = 0; ks < 2; ++ks)                        \
    DST[mf][ks] = *(const f16x8*)((PB) + ((MH) * 64 + mf * 16 + l15) * 64 \
                                  + (((ks * 4 + lhi) ^ (l15 & 7)) * 8));

#define RD_B(DST, PB, BO, NH)                                             \
  _Pragma("unroll") for (int nf = 0; nf < 2; ++nf)                        \
  _Pragma("unroll") for (int ks = 0; ks < 2; ++ks)                        \
    DST[nf][ks] = *(const f16x8*)((PB) + ((BO) + (NH) * 32 + nf * 16 + l15) * 64 \
                                  + (((ks * 4 + lhi) ^ (l15 & 7)) * 8));

#define MM(AV, BV, MB, NB2)                                               \
  __builtin_amdgcn_s_setprio(1);                                          \
  _Pragma("unroll") for (int mf = 0; mf < 4; ++mf)                        \
  _Pragma("unroll") for (int nf = 0; nf < 2; ++nf)                        \
  _Pragma("unroll") for (int ks = 0; ks < 2; ++ks)                        \
    acc[(MB) * 4 + mf][(NB2) * 2 + nf] =                                  \
        mfma16h(AV[mf][ks], BV[nf][ks], acc[(MB) * 4 + mf][(NB2) * 2 + nf]); \
  __builtin_amdgcn_s_setprio(0);

  f32x4 acc[8][4];
#pragma unroll
  for (int i = 0; i < 8; ++i)
#pragma unroll
    for (int j = 0; j < 4; ++j) acc[i][j] = 0.f;

  const int bofs = (wn & 1) * 64;

// full tile = 8 quarters (A q0..q3, B q0..q3)
#define STAGE_TILE(DB, T)                                                 \
  STAGE_Q(&As[DB][0][0],    Ag, m0,       T);                             \
  STAGE_Q(&As[DB][0][4096], Ag, m0 + 64,  T);                             \
  STAGE_Q(&As[DB][1][0],    Ag, m0 + 128, T);                             \
  STAGE_Q(&As[DB][1][4096], Ag, m0 + 192, T);                             \
  STAGE_Q(&Bs[DB][0][0],    Bg, n0,       T);                             \
  STAGE_Q(&Bs[DB][0][4096], Bg, n0 + 64,  T);                             \
  STAGE_Q(&Bs[DB][1][0],    Bg, n0 + 128, T);                             \
  STAGE_Q(&Bs[DB][1][4096], Bg, n0 + 192, T)

  // prologue: tile0 -> dbuf0 (oldest 8 loads), tile1 -> dbuf1
  STAGE_TILE(0, 0);
  STAGE_TILE(1, 1);
  VMC8();          // tile0's 8 landed; tile1's 8 in flight
  BAR();

#define PHASES4(DB, TN, PRE)                                              \
  {                                                                       \
    const u16* Apb = &As[DB][wm][0];                                      \
    const u16* Bpb = &Bs[DB][wn >> 1][0];                                 \
    /* ph0: (a0,b0); no stages */                                         \
    RD_A(a0, Apb, 0);                                                     \
    RD_B(b0, Bpb, bofs, 0);                                               \
    BAR();                                                                \
    LGKM0();                                                              \
    MM(a0, b0, 0, 0);                                                     \
    BAR();                                                                \
    /* ph1: (a0,b1); stage A q0,q2 of TN (a0 regions, last read ph0) */   \
    RD_B(b1, Bpb, bofs, 1);                                               \
    if (PRE) { STAGE_Q(&As[DB][0][0], Ag, m0,       TN);                  \
               STAGE_Q(&As[DB][1][0], Ag, m0 + 128, TN); }                \
    BAR();                                                                \
    LGKM0();                                                              \
    MM(a0, b1, 0, 1);                                                     \
    BAR();                                                                \
    /* ph2: (a1,b1); stage all B quarters of TN (B fully read after ph1) */ \
    RD_A(a1, Apb, 1);                                                     \
    if (PRE) { STAGE_Q(&Bs[DB][0][0],    Bg, n0,       TN);               \
               STAGE_Q(&Bs[DB][0][4096], Bg, n0 + 64,  TN);               \
               STAGE_Q(&Bs[DB][1][0],    Bg, n0 + 128, TN);               \
               STAGE_Q(&Bs[DB][1][4096], Bg, n0 + 192, TN); }             \
    BAR();                                                                \
    LGKM0();                                                              \
    MM(a1, b1, 1, 1);                                                     \
    BAR();                                                                \
    /* ph3: (a1,b0) regs only; stage A q1,q3 of TN (a1 regions, read ph2) */ \
    if (PRE) { STAGE_Q(&As[DB][0][4096], Ag, m0 + 64,  TN);               \
               STAGE_Q(&As[DB][1][4096], Ag, m0 + 192, TN); }             \
    BAR();                                                                \
    LGKM0();                                                              \
    MM(a1, b0, 1, 0);                                                     \
    if (PRE) { VMC8(); } else { VMC0(); }                                 \
    BAR();                                                                \
  }

  for (int it = 0; it < NT / 2; ++it) {
    const int t0 = 2 * it;
    const bool pre = (t0 + 2 < NT);
    f16x8 a0[4][2], a1[4][2], b0[2][2], b1[2][2];
    PHASES4(0, t0 + 2, pre)   // tile 2i
    PHASES4(1, t0 + 3, pre)   // tile 2i+1
  }
#undef PHASES4
#undef STAGE_TILE
#undef STAGE_Q
#undef BAR
#undef LGKM0
#undef VMC8
#undef VMC0
#undef RD_A
#undef RD_B
#undef MM

  // ---------------- epilogues (wave tile rows wm*128, cols wn*64) ----------------
  if (EPI == 2) {
    float bv[4];
#pragma unroll
    for (int cf = 0; cf < 4; ++cf) bv[cf] = bias[n0 + wn * 64 + cf * 16 + l15];
    const int region = n0 >> 10;
    const int ncol0 = (n0 & 1023) + wn * 64;
    if (region < 2) {
      u16* dst = region ? D1 : D0;
#pragma unroll
      for (int rf = 0; rf < 8; ++rf) {
        const int m = m0 + wm * 128 + rf * 16 + lhi * 4;
#pragma unroll
        for (int r = 0; r < 4; ++r)
#pragma unroll
          for (int cf = 0; cf < 4; ++cf)
            dst[(size_t)(m + r) * 1024 + ncol0 + cf * 16 + l15] = h1(acc[rf][cf][r] + bv[cf]);
      }
    } else {
#pragma unroll
      for (int rf = 0; rf < 8; ++rf) {
        const int m = m0 + wm * 128 + rf * 16 + lhi * 4;
        const int bb = m >> 12, s = m & 4095;
#pragma unroll
        for (int cf = 0; cf < 4; ++cf) {
          const int dcol = ncol0 + cf * 16 + l15;
          uint2 v;
          v.x = pk2h(acc[rf][cf][0] + bv[cf], acc[rf][cf][1] + bv[cf]);
          v.y = pk2h(acc[rf][cf][2] + bv[cf], acc[rf][cf][3] + bv[cf]);
          *(uint2*)&D2[(size_t)(bb * 1024 + dcol) * 4096 + s] = v;
        }
      }
    }
  } else if (EPI == 0) {
#pragma unroll
    for (int rf = 0; rf < 8; ++rf) {
      const int m = m0 + wm * 128 + rf * 16 + lhi * 4;
#pragma unroll
      for (int r = 0; r < 4; ++r)
#pragma unroll
        for (int cf = 0; cf < 4; ++cf) {
          const int n = n0 + wn * 64 + cf * 16 + l15;
          D0[(size_t)blockIdx.z * strC + (size_t)(m + r) * ldc + n] = h1(acc[rf][cf][r] * 0.03125f);
        }
    }
  } else {
#pragma unroll
    for (int rf = 0; rf < 8; ++rf) {
      const int m = m0 + wm * 128 + rf * 16 + lhi * 4;
#pragma unroll
      for (int r = 0; r < 4; ++r)
#pragma unroll
        for (int cf = 0; cf < 4; ++cf) {
          const int n = n0 + wn * 64 + cf * 16 + l15;
          Df[(size_t)blockIdx.z * strC + (size_t)(m + r) * ldc + n] = acc[rf][cf][r];
        }
    }
  }
}

// ---------------- row softmax, in place, f16. 1 block = 1 row of 4096 ----------------
__global__ __launch_bounds__(256) void softmax_k(u16* __restrict__ S) {
  const int tid = threadIdx.x, lane = tid & 63, wid = tid >> 6;
  u16* rp = S + (size_t)blockIdx.x * 4096;
  __shared__ float redm[4], reds[4];

  uint4 a = *(const uint4*)(rp + tid * 8);
  uint4 b = *(const uint4*)(rp + 2048 + tid * 8);
  float v[16];
  {
    union { uint4 q; u16 s[8]; } ua, ub;
    ua.q = a; ub.q = b;
#pragma unroll
    for (int i = 0; i < 8; ++i) { v[i] = h2f(ua.s[i]); v[8 + i] = h2f(ub.s[i]); }
  }
  float m = v[0];
#pragma unroll
  for (int i = 1; i < 16; ++i) m = fmaxf(m, v[i]);
#pragma unroll
  for (int o = 32; o; o >>= 1) m = fmaxf(m, __shfl_xor(m, o, 64));
  if (lane == 0) redm[wid] = m;
  __syncthreads();
  m = fmaxf(fmaxf(redm[0], redm[1]), fmaxf(redm[2], redm[3]));

  float s = 0.f;
#pragma unroll
  for (int i = 0; i < 16; ++i) { v[i] = EXP2F((v[i] - m) * LOG2E); s += v[i]; }
#pragma unroll
  for (int o = 32; o; o >>= 1) s += __shfl_xor(s, o, 64);
  if (lane == 0) reds[wid] = s;
  __syncthreads();
  const float inv = 1.0f / (reds[0] + reds[1] + reds[2] + reds[3]);

  uint4 oa, ob;
  oa.x = pk2h(v[0] * inv, v[1] * inv);   oa.y = pk2h(v[2] * inv, v[3] * inv);
  oa.z = pk2h(v[4] * inv, v[5] * inv);   oa.w = pk2h(v[6] * inv, v[7] * inv);
  ob.x = pk2h(v[8] * inv, v[9] * inv);   ob.y = pk2h(v[10] * inv, v[11] * inv);
  ob.z = pk2h(v[12] * inv, v[13] * inv); ob.w = pk2h(v[14] * inv, v[15] * inv);
  *(uint4*)(rp + tid * 8) = oa;
  *(uint4*)(rp + 2048 + tid * 8) = ob;
}

// ---------------- host ----------------
extern "C" void kernel_launch(void* const* d_in, const int* in_sizes, int n_in,
                              void* d_out, int out_size, void* d_ws, size_t ws_size,
                              hipStream_t stream) {
  const float* X = (const float*)d_in[0];   // [4,4096,1024]
  const float* W = (const float*)d_in[1];   // [3072,1024]
  const float* b = (const float*)d_in[2];   // [3072]
  float* out = (float*)d_out;               // [4,4096,1024] fp32
  char* ws = (char*)d_ws;

  const size_t SB = (size_t)4096 * 4096 * 2;          // S bytes per batch
  const size_t QB = (size_t)4096 * 1024 * 2;
  const size_t WFB = (size_t)3072 * 1024 * 2;
  int NB = 1;
  if (ws_size >= 4 * SB + WFB + 12 * QB) NB = 4;
  else if (ws_size >= 2 * SB + WFB + 12 * QB) NB = 2;

  u16* S  = (u16*)(ws);
  u16* Xf = (u16*)(ws);                               // overlay; dead after QKV proj
  u16* Wf = (u16*)(ws + (size_t)NB * SB);
  u16* Qf = (u16*)(ws + (size_t)NB * SB + WFB);
  u16* Kf = (u16*)(ws + (size_t)NB * SB + WFB + 4 * QB);
  u16* Vt = (u16*)(ws + (size_t)NB * SB + WFB + 8 * QB);

  cast_f16_k<<<8192, 256, 0, stream>>>(X, Xf, 16777216 / 8);
  cast_f16_k<<<1536, 256, 0, stream>>>(W, Wf, 3145728 / 8);

  // QKV projection: M=16384, N=3072, K=1024
  gemm8p<1024, 2><<<dim3(64, 12, 1), 512, 0, stream>>>(
      Xf, Wf, b, Qf, Kf, Vt, nullptr, 0, 0, 0, 0);

  const size_t strQ = (size_t)4096 * 1024;
  const size_t strS = (size_t)4096 * 4096;
  const size_t strV = (size_t)1024 * 4096;
  for (int g = 0; g < 4; g += NB) {
    const u16* Qg = Qf + (size_t)g * strQ;
    const u16* Kg = Kf + (size_t)g * strQ;
    const u16* Vg = Vt + (size_t)g * strV;
    float* Og = out + (size_t)g * strQ;
    // S = Q K^T / 32  [4096x4096] x NB
    gemm8p<1024, 0><<<dim3(16, 16, NB), 512, 0, stream>>>(
        Qg, Kg, nullptr, S, nullptr, nullptr, nullptr, 4096, strQ, strQ, strS);
    softmax_k<<<4096 * NB, 256, 0, stream>>>(S);
    // O = P Vt^T  [4096x1024] x NB
    gemm8p<4096, 1><<<dim3(16, 4, NB), 512, 0, stream>>>(
        S, Vg, nullptr, nullptr, nullptr, nullptr, Og, 1024, strS, strV, strQ);
  }
}

// Round 11
// 432.434 us; speedup vs baseline: 1.1207x; 1.1207x over previous
//
#include <hip/hip_runtime.h>
#include <hip/hip_bf16.h>

typedef unsigned short u16;
typedef _Float16 f16x8 __attribute__((ext_vector_type(8)));
typedef float f32x4 __attribute__((ext_vector_type(4)));

#if __has_builtin(__builtin_amdgcn_exp2f)
#define EXP2F(x) __builtin_amdgcn_exp2f(x)
#else
#define EXP2F(x) exp2f(x)
#endif
// log2(e)/32 : p = exp2(acc * FA_C32) = exp(acc/32)
#define FA_C32 0.045084220027780106f

__device__ __forceinline__ f32x4 mfma16h(f16x8 a, f16x8 b, f32x4 c) {
  return __builtin_amdgcn_mfma_f32_16x16x32_f16(a, b, c, 0, 0, 0);
}
__device__ __forceinline__ unsigned pk2h(float a, float b) {
  union { _Float16 h[2]; unsigned u; } x;
  x.h[0] = (_Float16)a; x.h[1] = (_Float16)b;
  return x.u;
}
__device__ __forceinline__ u16 h1(float a) {
  union { _Float16 h; u16 u; } x; x.h = (_Float16)a; return x.u;
}

typedef __attribute__((address_space(1))) const unsigned int gas_u32;
typedef __attribute__((address_space(3))) unsigned int las_u32;
__device__ __forceinline__ void gl_lds16(const u16* g, u16* l) {
  __builtin_amdgcn_global_load_lds((gas_u32*)g, (las_u32*)l, 16, 0, 0);
}

// ---------------- cast fp32 -> f16, 8 elems/thread ----------------
__global__ __launch_bounds__(256) void cast_f16_k(const float* __restrict__ src,
                                                  u16* __restrict__ dst, int n8) {
  int i = blockIdx.x * 256 + threadIdx.x;
  if (i >= n8) return;
  const float4* s4 = (const float4*)src;
  float4 a = s4[i * 2], b = s4[i * 2 + 1];
  uint4 o;
  o.x = pk2h(a.x, a.y); o.y = pk2h(a.z, a.w);
  o.z = pk2h(b.x, b.y); o.w = pk2h(b.z, b.w);
  ((uint4*)dst)[i] = o;
}

// ---------------- row-sum finalize: linv[z][row] = 1/sum_by partial ----------------
__global__ __launch_bounds__(256) void reduce_l_k(const float* __restrict__ partial,
                                                  float* __restrict__ linv, int nrows) {
  int i = blockIdx.x * 256 + threadIdx.x;
  if (i >= nrows) return;
  const int z = i >> 12, row = i & 4095;
  const float* p = partial + (size_t)z * 16 * 4096 + row;
  float s = 0.f;
#pragma unroll
  for (int by = 0; by < 16; ++by) s += p[(size_t)by * 4096];
  linv[i] = 1.0f / s;
}

// =================================================================
// 8-phase GEMM (round-9 proven sync structure, byte-identical K-loop):
// BM=BN=256, BK=64, 8 waves (2Mx4N), acc 8x4, quarter-granularity staging.
//   ph0: read a0,b0 | ph1: read b1, stage A q0,q2(+2) | ph2: read a1, stage
//   B q0..q3(+2) | ph3: regs only, stage A q1,q3(+2); vmcnt(8) at ph3/ph7.
// Round-11: softmax fused into epilogues (no loop/sync change):
//   EPI=0: D0 f16 = exp(acc/32) (clamped); per-block row sums -> Pr[z][by][m]
//   EPI=1: Df f32 = acc * Lv[z][m]   (Lv = 1/rowsum from reduce_l_k)
//   EPI=2: QKV scatter (Q,K row-major; V -> Vt[b][d][s])
// =================================================================
template <int K_, int EPI>
__global__ __launch_bounds__(512, 2) void gemm8p(
    const u16* __restrict__ A, const u16* __restrict__ B,
    const float* __restrict__ bias, u16* __restrict__ D0, u16* __restrict__ D1,
    u16* __restrict__ D2, float* __restrict__ Df, const int ldc,
    const size_t strA, const size_t strB, const size_t strC,
    float* __restrict__ Pr, const float* __restrict__ Lv) {
  constexpr int NT = K_ / 64;
  static_assert(NT >= 4 && (NT % 2) == 0, "need even NT >= 4");
  __shared__ __align__(16) u16 As[2][2][128 * 64];   // [dbuf][M-half]
  __shared__ __align__(16) u16 Bs[2][2][128 * 64];   // [dbuf][N-half]

  const int tid = threadIdx.x, lane = tid & 63, wid = tid >> 6;
  const int l15 = lane & 15, lhi = lane >> 4;
  const int m0 = blockIdx.x * 256, n0 = blockIdx.y * 256;
  const int wm = wid >> 2, wn = wid & 3;
  const u16* Ag = A + (size_t)blockIdx.z * strA;
  const u16* Bg = B + (size_t)blockIdx.z * strB;

  const int srow8 = lane >> 3;              // LDS row & 7 for this lane's 16B
  const int sblk = (lane & 7) ^ srow8;      // source block XOR (T2 both-sides)

// one 64-row quarter: 1 global_load_lds per wave (8 rows/wave)
#define STAGE_Q(BUF, G, GROW0, ST)                                        \
  gl_lds16((G) + (size_t)((GROW0) + wid * 8 + srow8) * K_ +               \
               (ST) * 64 + sblk * 8,                                      \
           (BUF) + (wid * 8) * 64)

#define BAR()                                                             \
  asm volatile("" ::: "memory");                                          \
  __builtin_amdgcn_s_barrier();                                           \
  asm volatile("" ::: "memory")

#define LGKM0()                                                           \
  asm volatile("s_waitcnt lgkmcnt(0)" ::: "memory");                      \
  __builtin_amdgcn_sched_barrier(0)

#define SB0() __builtin_amdgcn_sched_barrier(0)
#define VMC8() asm volatile("s_waitcnt vmcnt(8)" ::: "memory")
#define VMC0() asm volatile("s_waitcnt vmcnt(0)" ::: "memory")

#define RD_A(DST, PB, MH)                                                 \
  _Pragma("unroll") for (int mf = 0; mf < 4; ++mf)                        \
  _Pragma("unroll") for (int ks = 0; ks < 2; ++ks)                        \
    DST[mf][ks] = *(const f16x8*)((PB) + ((MH) * 64 + mf * 16 + l15) * 64 \
                                  + (((ks * 4 + lhi) ^ (l15 & 7)) * 8));

#define RD_B(DST, PB, BO, NH)                                             \
  _Pragma("unroll") for (int nf = 0; nf < 2; ++nf)                        \
  _Pragma("unroll") for (int ks = 0; ks < 2; ++ks)                        \
    DST[nf][ks] = *(const f16x8*)((PB) + ((BO) + (NH) * 32 + nf * 16 + l15) * 64 \
                                  + (((ks * 4 + lhi) ^ (l15 & 7)) * 8));

#define MM(AV, BV, MB, NB2)                                               \
  __builtin_amdgcn_s_setprio(1);                                          \
  _Pragma("unroll") for (int mf = 0; mf < 4; ++mf)                        \
  _Pragma("unroll") for (int nf = 0; nf < 2; ++nf)                        \
  _Pragma("unroll") for (int ks = 0; ks < 2; ++ks)                        \
    acc[(MB) * 4 + mf][(NB2) * 2 + nf] =                                  \
        mfma16h(AV[mf][ks], BV[nf][ks], acc[(MB) * 4 + mf][(NB2) * 2 + nf]); \
  __builtin_amdgcn_s_setprio(0);

  f32x4 acc[8][4];
#pragma unroll
  for (int i = 0; i < 8; ++i)
#pragma unroll
    for (int j = 0; j < 4; ++j) acc[i][j] = 0.f;

  const int bofs = (wn & 1) * 64;

// full tile = 8 quarters (A q0..q3, B q0..q3)
#define STAGE_TILE(DB, T)                                                 \
  STAGE_Q(&As[DB][0][0],    Ag, m0,       T);                             \
  STAGE_Q(&As[DB][0][4096], Ag, m0 + 64,  T);                             \
  STAGE_Q(&As[DB][1][0],    Ag, m0 + 128, T);                             \
  STAGE_Q(&As[DB][1][4096], Ag, m0 + 192, T);                             \
  STAGE_Q(&Bs[DB][0][0],    Bg, n0,       T);                             \
  STAGE_Q(&Bs[DB][0][4096], Bg, n0 + 64,  T);                             \
  STAGE_Q(&Bs[DB][1][0],    Bg, n0 + 128, T);                             \
  STAGE_Q(&Bs[DB][1][4096], Bg, n0 + 192, T)

  // prologue: tile0 -> dbuf0 (oldest 8 loads), tile1 -> dbuf1
  STAGE_TILE(0, 0);
  STAGE_TILE(1, 1);
  VMC8();          // tile0's 8 landed; tile1's 8 in flight
  BAR();

#define PHASES4(DB, TN, PRE)                                              \
  {                                                                       \
    const u16* Apb = &As[DB][wm][0];                                      \
    const u16* Bpb = &Bs[DB][wn >> 1][0];                                 \
    /* ph0: (a0,b0); no stages */                                         \
    RD_A(a0, Apb, 0);                                                     \
    RD_B(b0, Bpb, bofs, 0);                                               \
    BAR();                                                                \
    LGKM0();                                                              \
    MM(a0, b0, 0, 0);                                                     \
    SB0();                                                                \
    BAR();                                                                \
    /* ph1: (a0,b1); stage A q0,q2 of TN (a0 regions, last read ph0) */   \
    RD_B(b1, Bpb, bofs, 1);                                               \
    if (PRE) { STAGE_Q(&As[DB][0][0], Ag, m0,       TN);                  \
               STAGE_Q(&As[DB][1][0], Ag, m0 + 128, TN); }                \
    BAR();                                                                \
    LGKM0();                                                              \
    MM(a0, b1, 0, 1);                                                     \
    SB0();                                                                \
    BAR();                                                                \
    /* ph2: (a1,b1); stage all B quarters of TN (B fully read after ph1) */ \
    RD_A(a1, Apb, 1);                                                     \
    if (PRE) { STAGE_Q(&Bs[DB][0][0],    Bg, n0,       TN);               \
               STAGE_Q(&Bs[DB][0][4096], Bg, n0 + 64,  TN);               \
               STAGE_Q(&Bs[DB][1][0],    Bg, n0 + 128, TN);               \
               STAGE_Q(&Bs[DB][1][4096], Bg, n0 + 192, TN); }             \
    BAR();                                                                \
    LGKM0();                                                              \
    MM(a1, b1, 1, 1);                                                     \
    SB0();                                                                \
    BAR();                                                                \
    /* ph3: (a1,b0) regs only; stage A q1,q3 of TN (a1 regions, read ph2) */ \
    if (PRE) { STAGE_Q(&As[DB][0][4096], Ag, m0 + 64,  TN);               \
               STAGE_Q(&As[DB][1][4096], Ag, m0 + 192, TN); }             \
    BAR();                                                                \
    LGKM0();                                                              \
    MM(a1, b0, 1, 0);                                                     \
    SB0();                                                                \
    if (PRE) { VMC8(); } else { VMC0(); }                                 \
    BAR();                                                                \
  }

  for (int it = 0; it < NT / 2; ++it) {
    const int t0 = 2 * it;
    const bool pre = (t0 + 2 < NT);
    f16x8 a0[4][2], a1[4][2], b0[2][2], b1[2][2];
    PHASES4(0, t0 + 2, pre)   // tile 2i
    PHASES4(1, t0 + 3, pre)   // tile 2i+1
  }
#undef PHASES4
#undef STAGE_TILE
#undef STAGE_Q
#undef BAR
#undef LGKM0
#undef SB0
#undef VMC8
#undef VMC0
#undef RD_A
#undef RD_B
#undef MM

  // ---------------- epilogues (wave tile rows wm*128, cols wn*64) ----------------
  if (EPI == 2) {
    float bv[4];
#pragma unroll
    for (int cf = 0; cf < 4; ++cf) bv[cf] = bias[n0 + wn * 64 + cf * 16 + l15];
    const int region = n0 >> 10;
    const int ncol0 = (n0 & 1023) + wn * 64;
    if (region < 2) {
      u16* dst = region ? D1 : D0;
#pragma unroll
      for (int rf = 0; rf < 8; ++rf) {
        const int m = m0 + wm * 128 + rf * 16 + lhi * 4;
#pragma unroll
        for (int r = 0; r < 4; ++r)
#pragma unroll
          for (int cf = 0; cf < 4; ++cf)
            dst[(size_t)(m + r) * 1024 + ncol0 + cf * 16 + l15] = h1(acc[rf][cf][r] + bv[cf]);
      }
    } else {
#pragma unroll
      for (int rf = 0; rf < 8; ++rf) {
        const int m = m0 + wm * 128 + rf * 16 + lhi * 4;
        const int bb = m >> 12, s = m & 4095;
#pragma unroll
        for (int cf = 0; cf < 4; ++cf) {
          const int dcol = ncol0 + cf * 16 + l15;
          uint2 v;
          v.x = pk2h(acc[rf][cf][0] + bv[cf], acc[rf][cf][1] + bv[cf]);
          v.y = pk2h(acc[rf][cf][2] + bv[cf], acc[rf][cf][3] + bv[cf]);
          *(uint2*)&D2[(size_t)(bb * 1024 + dcol) * 4096 + s] = v;
        }
      }
    }
  } else if (EPI == 0) {
    // p = exp(acc/32); store f16; per-block row sums -> Pr[z][by][m]
    // (As LDS reusable: final BAR follows every wave's lgkmcnt(0))
    float* rsum = (float*)&As[0][0][0];        // [4 wn][256 rows] f32
#pragma unroll
    for (int rf = 0; rf < 8; ++rf)
#pragma unroll
      for (int r = 0; r < 4; ++r) {
        float s = 0.f;
#pragma unroll
        for (int cf = 0; cf < 4; ++cf) {
          float p = EXP2F(acc[rf][cf][r] * FA_C32);
          p = fminf(p, 60000.f);               // f16-overflow guard (11-sigma)
          acc[rf][cf][r] = p;
          s += p;
        }
        s += __shfl_xor(s, 1, 64);
        s += __shfl_xor(s, 2, 64);
        s += __shfl_xor(s, 4, 64);
        s += __shfl_xor(s, 8, 64);
        if (l15 == 0) rsum[wn * 256 + wm * 128 + rf * 16 + lhi * 4 + r] = s;
      }
#pragma unroll
    for (int rf = 0; rf < 8; ++rf) {
      const int m = m0 + wm * 128 + rf * 16 + lhi * 4;
#pragma unroll
      for (int r = 0; r < 4; ++r)
#pragma unroll
        for (int cf = 0; cf < 4; ++cf) {
          const int n = n0 + wn * 64 + cf * 16 + l15;
          D0[(size_t)blockIdx.z * strC + (size_t)(m + r) * ldc + n] = h1(acc[rf][cf][r]);
        }
    }
    __syncthreads();
    if (tid < 256) {
      const float s = rsum[tid] + rsum[256 + tid] + rsum[512 + tid] + rsum[768 + tid];
      Pr[((size_t)blockIdx.z * 16 + blockIdx.y) * 4096 + m0 + tid] = s;
    }
  } else {
    // Df = acc * linv[row]
#pragma unroll
    for (int rf = 0; rf < 8; ++rf) {
      const int m = m0 + wm * 128 + rf * 16 + lhi * 4;
#pragma unroll
      for (int r = 0; r < 4; ++r) {
        const float li = Lv[(size_t)blockIdx.z * 4096 + m + r];
#pragma unroll
        for (int cf = 0; cf < 4; ++cf) {
          const int n = n0 + wn * 64 + cf * 16 + l15;
          Df[(size_t)blockIdx.z * strC + (size_t)(m + r) * ldc + n] = acc[rf][cf][r] * li;
        }
      }
    }
  }
}

// ---------------- host ----------------
extern "C" void kernel_launch(void* const* d_in, const int* in_sizes, int n_in,
                              void* d_out, int out_size, void* d_ws, size_t ws_size,
                              hipStream_t stream) {
  const float* X = (const float*)d_in[0];   // [4,4096,1024]
  const float* W = (const float*)d_in[1];   // [3072,1024]
  const float* b = (const float*)d_in[2];   // [3072]
  float* out = (float*)d_out;               // [4,4096,1024] fp32
  char* ws = (char*)d_ws;

  const size_t SB = (size_t)4096 * 4096 * 2;          // S bytes per batch
  const size_t QB = (size_t)4096 * 1024 * 2;
  const size_t WFB = (size_t)3072 * 1024 * 2;
  int NB = 1;
  if (ws_size >= 4 * SB + WFB + 12 * QB) NB = 4;
  else if (ws_size >= 2 * SB + WFB + 12 * QB) NB = 2;

  u16* S  = (u16*)(ws);
  u16* Xf = (u16*)(ws);                               // overlay; dead after QKV proj
  u16* Wf = (u16*)(ws + (size_t)NB * SB);
  u16* Qf = (u16*)(ws + (size_t)NB * SB + WFB);
  u16* Kf = (u16*)(ws + (size_t)NB * SB + WFB + 4 * QB);
  u16* Vt = (u16*)(ws + (size_t)NB * SB + WFB + 8 * QB);
  // Wf region (6.29 MB) is dead after gemm_qkv; overlay row-sum buffers there:
  float* Pr = (float*)Wf;                             // [NB][16][4096] = 1 MB max
  float* Lv = Pr + (size_t)NB * 16 * 4096;            // [NB][4096]

  cast_f16_k<<<8192, 256, 0, stream>>>(X, Xf, 16777216 / 8);
  cast_f16_k<<<1536, 256, 0, stream>>>(W, Wf, 3145728 / 8);

  // QKV projection: M=16384, N=3072, K=1024
  gemm8p<1024, 2><<<dim3(64, 12, 1), 512, 0, stream>>>(
      Xf, Wf, b, Qf, Kf, Vt, nullptr, 0, 0, 0, 0, nullptr, nullptr);

  const size_t strQ = (size_t)4096 * 1024;
  const size_t strS = (size_t)4096 * 4096;
  const size_t strV = (size_t)1024 * 4096;
  for (int g = 0; g < 4; g += NB) {
    const u16* Qg = Qf + (size_t)g * strQ;
    const u16* Kg = Kf + (size_t)g * strQ;
    const u16* Vg = Vt + (size_t)g * strV;
    float* Og = out + (size_t)g * strQ;
    // S = exp(Q K^T / 32)  [4096x4096] x NB, + per-block row sums
    gemm8p<1024, 0><<<dim3(16, 16, NB), 512, 0, stream>>>(
        Qg, Kg, nullptr, S, nullptr, nullptr, nullptr, 4096, strQ, strQ, strS,
        Pr, nullptr);
    // linv = 1 / rowsum
    reduce_l_k<<<NB * 16, 256, 0, stream>>>(Pr, Lv, NB * 4096);
    // O = (S Vt^T) * linv  [4096x1024] x NB
    gemm8p<4096, 1><<<dim3(16, 4, NB), 512, 0, stream>>>(
        S, Vg, nullptr, nullptr, nullptr, nullptr, Og, 1024, strS, strV, strQ,
        nullptr, Lv);
  }
}

// Round 13
// 417.392 us; speedup vs baseline: 1.1611x; 1.0360x over previous
//
#include <hip/hip_runtime.h>
#include <hip/hip_bf16.h>

typedef unsigned short u16;
typedef _Float16 f16x8 __attribute__((ext_vector_type(8)));
typedef _Float16 f16x2 __attribute__((ext_vector_type(2)));
typedef float f32x4 __attribute__((ext_vector_type(4)));

#if __has_builtin(__builtin_amdgcn_exp2f)
#define EXP2F(x) __builtin_amdgcn_exp2f(x)
#else
#define EXP2F(x) exp2f(x)
#endif
// log2(e)/32 : p = exp2(acc * FA_C32) = exp(acc/32)
#define FA_C32 0.045084220027780106f

__device__ __forceinline__ f32x4 mfma16h(f16x8 a, f16x8 b, f32x4 c) {
  return __builtin_amdgcn_mfma_f32_16x16x32_f16(a, b, c, 0, 0, 0);
}
__device__ __forceinline__ unsigned pk2h(float a, float b) {
  union { _Float16 h[2]; unsigned u; } x;
  x.h[0] = (_Float16)a; x.h[1] = (_Float16)b;
  return x.u;
}
__device__ __forceinline__ u16 h1(float a) {
  union { _Float16 h; u16 u; } x; x.h = (_Float16)a; return x.u;
}

#if __has_builtin(__builtin_amdgcn_fdot2)
__device__ __forceinline__ float fdot2_(f16x2 a, f16x2 b, float c) {
  return __builtin_amdgcn_fdot2(a, b, c, false);
}
#else
__device__ __forceinline__ float fdot2_(f16x2 a, f16x2 b, float c) {
  return c + (float)a[0] * (float)b[0] + (float)a[1] * (float)b[1];
}
#endif

typedef __attribute__((address_space(1))) const unsigned int gas_u32;
typedef __attribute__((address_space(3))) unsigned int las_u32;
__device__ __forceinline__ void gl_lds16(const u16* g, u16* l) {
  __builtin_amdgcn_global_load_lds((gas_u32*)g, (las_u32*)l, 16, 0, 0);
}

// ---------------- cast fp32 -> f16, 8 elems/thread ----------------
__global__ __launch_bounds__(256) void cast_f16_k(const float* __restrict__ src,
                                                  u16* __restrict__ dst, int n8) {
  int i = blockIdx.x * 256 + threadIdx.x;
  if (i >= n8) return;
  const float4* s4 = (const float4*)src;
  float4 a = s4[i * 2], b = s4[i * 2 + 1];
  uint4 o;
  o.x = pk2h(a.x, a.y); o.y = pk2h(a.z, a.w);
  o.z = pk2h(b.x, b.y); o.w = pk2h(b.z, b.w);
  ((uint4*)dst)[i] = o;
}

// =================================================================
// 8-phase GEMM (round-9 proven sync structure, byte-identical K-loop):
// BM=BN=256, BK=64, 8 waves (2Mx4N), acc 8x4, quarter-granularity staging.
//   ph0: read a0,b0 | ph1: read b1, stage A q0,q2(+2) | ph2: read a1, stage
//   B q0..q3(+2) | ph3: regs only, stage A q1,q3(+2); vmcnt(8) at ph3/ph7.
// Round-13 (= round-12 intent, compile-fixed): row-sum fused into gemm3
// (EPI=1): wn==0 waves accumulate l_row = sum_k P[row][k] via fdot2 on their
// A-fragments (register-only, placed after MM — no sync-structure change),
// reduce via 2 shfl + 1 KB LDS, epilogue scales by 1/l.
// gemm2 (EPI=0) epilogue = exp+store only.
//   EPI=0: D0 f16 = exp(acc/32) (clamped)
//   EPI=1: Df f32 = acc / l_row
//   EPI=2: QKV scatter (Q,K row-major; V -> Vt[b][d][s])
// =================================================================
template <int K_, int EPI>
__global__ __launch_bounds__(512, 2) void gemm8p(
    const u16* __restrict__ A, const u16* __restrict__ B,
    const float* __restrict__ bias, u16* __restrict__ D0, u16* __restrict__ D1,
    u16* __restrict__ D2, float* __restrict__ Df, const int ldc,
    const size_t strA, const size_t strB, const size_t strC) {
  constexpr int NT = K_ / 64;
  static_assert(NT >= 4 && (NT % 2) == 0, "need even NT >= 4");
  __shared__ __align__(16) u16 As[2][2][128 * 64];   // [dbuf][M-half]
  __shared__ __align__(16) u16 Bs[2][2][128 * 64];   // [dbuf][N-half]
  __shared__ float lds_l[256];                       // EPI=1 row sums

  const int tid = threadIdx.x, lane = tid & 63, wid = tid >> 6;
  const int l15 = lane & 15, lhi = lane >> 4;
  const int m0 = blockIdx.x * 256, n0 = blockIdx.y * 256;
  const int wm = wid >> 2, wn = wid & 3;
  const u16* Ag = A + (size_t)blockIdx.z * strA;
  const u16* Bg = B + (size_t)blockIdx.z * strB;

  const int srow8 = lane >> 3;              // LDS row & 7 for this lane's 16B
  const int sblk = (lane & 7) ^ srow8;      // source block XOR (T2 both-sides)

// one 64-row quarter: 1 global_load_lds per wave (8 rows/wave)
#define STAGE_Q(BUF, G, GROW0, ST)                                        \
  gl_lds16((G) + (size_t)((GROW0) + wid * 8 + srow8) * K_ +               \
               (ST) * 64 + sblk * 8,                                      \
           (BUF) + (wid * 8) * 64)

#define BAR()                                                             \
  asm volatile("" ::: "memory");                                          \
  __builtin_amdgcn_s_barrier();                                           \
  asm volatile("" ::: "memory")

#define LGKM0()                                                           \
  asm volatile("s_waitcnt lgkmcnt(0)" ::: "memory");                      \
  __builtin_amdgcn_sched_barrier(0)

#define SB0() __builtin_amdgcn_sched_barrier(0)
#define VMC8() asm volatile("s_waitcnt vmcnt(8)" ::: "memory")
#define VMC0() asm volatile("s_waitcnt vmcnt(0)" ::: "memory")

#define RD_A(DST, PB, MH)                                                 \
  _Pragma("unroll") for (int mf = 0; mf < 4; ++mf)                        \
  _Pragma("unroll") for (int ks = 0; ks < 2; ++ks)                        \
    DST[mf][ks] = *(const f16x8*)((PB) + ((MH) * 64 + mf * 16 + l15) * 64 \
                                  + (((ks * 4 + lhi) ^ (l15 & 7)) * 8));

#define RD_B(DST, PB, BO, NH)                                             \
  _Pragma("unroll") for (int nf = 0; nf < 2; ++nf)                        \
  _Pragma("unroll") for (int ks = 0; ks < 2; ++ks)                        \
    DST[nf][ks] = *(const f16x8*)((PB) + ((BO) + (NH) * 32 + nf * 16 + l15) * 64 \
                                  + (((ks * 4 + lhi) ^ (l15 & 7)) * 8));

#define MM(AV, BV, MB, NB2)                                               \
  __builtin_amdgcn_s_setprio(1);                                          \
  _Pragma("unroll") for (int mf = 0; mf < 4; ++mf)                        \
  _Pragma("unroll") for (int nf = 0; nf < 2; ++nf)                        \
  _Pragma("unroll") for (int ks = 0; ks < 2; ++ks)                        \
    acc[(MB) * 4 + mf][(NB2) * 2 + nf] =                                  \
        mfma16h(AV[mf][ks], BV[nf][ks], acc[(MB) * 4 + mf][(NB2) * 2 + nf]); \
  __builtin_amdgcn_s_setprio(0);

// row-sum accumulate over an A fragment set (EPI=1, wn==0 waves only;
// register-only VALU; f16x2 pointer view constant-folds after full unroll)
#define SUMA(FR, MH8)                                                     \
  if (EPI == 1 && wn == 0) {                                              \
    _Pragma("unroll") for (int mf = 0; mf < 4; ++mf)                      \
    _Pragma("unroll") for (int ks = 0; ks < 2; ++ks) {                    \
      const f16x2* _pr = (const f16x2*)&FR[mf][ks];                       \
      _Pragma("unroll") for (int j = 0; j < 4; ++j)                       \
        lsa[MH8][mf] = fdot2_(_pr[j], ones2, lsa[MH8][mf]);               \
    }                                                                     \
  }

  f32x4 acc[8][4];
#pragma unroll
  for (int i = 0; i < 8; ++i)
#pragma unroll
    for (int j = 0; j < 4; ++j) acc[i][j] = 0.f;

  float lsa[2][4];
#pragma unroll
  for (int i = 0; i < 2; ++i)
#pragma unroll
    for (int j = 0; j < 4; ++j) lsa[i][j] = 0.f;
  const f16x2 ones2 = {(_Float16)1.0f, (_Float16)1.0f};

  const int bofs = (wn & 1) * 64;

// full tile = 8 quarters (A q0..q3, B q0..q3)
#define STAGE_TILE(DB, T)                                                 \
  STAGE_Q(&As[DB][0][0],    Ag, m0,       T);                             \
  STAGE_Q(&As[DB][0][4096], Ag, m0 + 64,  T);                             \
  STAGE_Q(&As[DB][1][0],    Ag, m0 + 128, T);                             \
  STAGE_Q(&As[DB][1][4096], Ag, m0 + 192, T);                             \
  STAGE_Q(&Bs[DB][0][0],    Bg, n0,       T);                             \
  STAGE_Q(&Bs[DB][0][4096], Bg, n0 + 64,  T);                             \
  STAGE_Q(&Bs[DB][1][0],    Bg, n0 + 128, T);                             \
  STAGE_Q(&Bs[DB][1][4096], Bg, n0 + 192, T)

  // prologue: tile0 -> dbuf0 (oldest 8 loads), tile1 -> dbuf1
  STAGE_TILE(0, 0);
  STAGE_TILE(1, 1);
  VMC8();          // tile0's 8 landed; tile1's 8 in flight
  BAR();

#define PHASES4(DB, TN, PRE)                                              \
  {                                                                       \
    const u16* Apb = &As[DB][wm][0];                                      \
    const u16* Bpb = &Bs[DB][wn >> 1][0];                                 \
    /* ph0: (a0,b0); no stages */                                         \
    RD_A(a0, Apb, 0);                                                     \
    RD_B(b0, Bpb, bofs, 0);                                               \
    BAR();                                                                \
    LGKM0();                                                              \
    MM(a0, b0, 0, 0);                                                     \
    SUMA(a0, 0);                                                          \
    SB0();                                                                \
    BAR();                                                                \
    /* ph1: (a0,b1); stage A q0,q2 of TN (a0 regions, last read ph0) */   \
    RD_B(b1, Bpb, bofs, 1);                                               \
    if (PRE) { STAGE_Q(&As[DB][0][0], Ag, m0,       TN);                  \
               STAGE_Q(&As[DB][1][0], Ag, m0 + 128, TN); }                \
    BAR();                                                                \
    LGKM0();                                                              \
    MM(a0, b1, 0, 1);                                                     \
    SB0();                                                                \
    BAR();                                                                \
    /* ph2: (a1,b1); stage all B quarters of TN (B fully read after ph1) */ \
    RD_A(a1, Apb, 1);                                                     \
    if (PRE) { STAGE_Q(&Bs[DB][0][0],    Bg, n0,       TN);               \
               STAGE_Q(&Bs[DB][0][4096], Bg, n0 + 64,  TN);               \
               STAGE_Q(&Bs[DB][1][0],    Bg, n0 + 128, TN);               \
               STAGE_Q(&Bs[DB][1][4096], Bg, n0 + 192, TN); }             \
    BAR();                                                                \
    LGKM0();                                                              \
    MM(a1, b1, 1, 1);                                                     \
    SUMA(a1, 1);                                                          \
    SB0();                                                                \
    BAR();                                                                \
    /* ph3: (a1,b0) regs only; stage A q1,q3 of TN (a1 regions, read ph2) */ \
    if (PRE) { STAGE_Q(&As[DB][0][4096], Ag, m0 + 64,  TN);               \
               STAGE_Q(&As[DB][1][4096], Ag, m0 + 192, TN); }             \
    BAR();                                                                \
    LGKM0();                                                              \
    MM(a1, b0, 1, 0);                                                     \
    SB0();                                                                \
    if (PRE) { VMC8(); } else { VMC0(); }                                 \
    BAR();                                                                \
  }

  for (int it = 0; it < NT / 2; ++it) {
    const int t0 = 2 * it;
    const bool pre = (t0 + 2 < NT);
    f16x8 a0[4][2], a1[4][2], b0[2][2], b1[2][2];
    PHASES4(0, t0 + 2, pre)   // tile 2i
    PHASES4(1, t0 + 3, pre)   // tile 2i+1
  }
#undef PHASES4
#undef STAGE_TILE
#undef STAGE_Q
#undef BAR
#undef LGKM0
#undef SB0
#undef VMC8
#undef VMC0
#undef RD_A
#undef RD_B
#undef MM
#undef SUMA

  // ---------------- epilogues (wave tile rows wm*128, cols wn*64) ----------------
  if (EPI == 2) {
    float bv[4];
#pragma unroll
    for (int cf = 0; cf < 4; ++cf) bv[cf] = bias[n0 + wn * 64 + cf * 16 + l15];
    const int region = n0 >> 10;
    const int ncol0 = (n0 & 1023) + wn * 64;
    if (region < 2) {
      u16* dst = region ? D1 : D0;
#pragma unroll
      for (int rf = 0; rf < 8; ++rf) {
        const int m = m0 + wm * 128 + rf * 16 + lhi * 4;
#pragma unroll
        for (int r = 0; r < 4; ++r)
#pragma unroll
          for (int cf = 0; cf < 4; ++cf)
            dst[(size_t)(m + r) * 1024 + ncol0 + cf * 16 + l15] = h1(acc[rf][cf][r] + bv[cf]);
      }
    } else {
#pragma unroll
      for (int rf = 0; rf < 8; ++rf) {
        const int m = m0 + wm * 128 + rf * 16 + lhi * 4;
        const int bb = m >> 12, s = m & 4095;
#pragma unroll
        for (int cf = 0; cf < 4; ++cf) {
          const int dcol = ncol0 + cf * 16 + l15;
          uint2 v;
          v.x = pk2h(acc[rf][cf][0] + bv[cf], acc[rf][cf][1] + bv[cf]);
          v.y = pk2h(acc[rf][cf][2] + bv[cf], acc[rf][cf][3] + bv[cf]);
          *(uint2*)&D2[(size_t)(bb * 1024 + dcol) * 4096 + s] = v;
        }
      }
    }
  } else if (EPI == 0) {
    // p = exp(acc/32), f16-clamped, store (row sums now computed in gemm3)
#pragma unroll
    for (int rf = 0; rf < 8; ++rf) {
      const int m = m0 + wm * 128 + rf * 16 + lhi * 4;
#pragma unroll
      for (int r = 0; r < 4; ++r)
#pragma unroll
        for (int cf = 0; cf < 4; ++cf) {
          const int n = n0 + wn * 64 + cf * 16 + l15;
          float p = fminf(EXP2F(acc[rf][cf][r] * FA_C32), 60000.f);
          D0[(size_t)blockIdx.z * strC + (size_t)(m + r) * ldc + n] = h1(p);
        }
    }
  } else {
    // publish row sums (lanes hold rows at l15; C rows live at lhi*4+r)
    if (wn == 0) {
#pragma unroll
      for (int mh = 0; mh < 2; ++mh)
#pragma unroll
        for (int mf = 0; mf < 4; ++mf) {
          float s = lsa[mh][mf];
          s += __shfl_xor(s, 16, 64);
          s += __shfl_xor(s, 32, 64);
          if (lhi == 0) lds_l[wm * 128 + mh * 64 + mf * 16 + l15] = s;
        }
    }
    __syncthreads();
#pragma unroll
    for (int rf = 0; rf < 8; ++rf) {
      const int m = m0 + wm * 128 + rf * 16 + lhi * 4;
#pragma unroll
      for (int r = 0; r < 4; ++r) {
        const float li = 1.0f / lds_l[wm * 128 + rf * 16 + lhi * 4 + r];
#pragma unroll
        for (int cf = 0; cf < 4; ++cf) {
          const int n = n0 + wn * 64 + cf * 16 + l15;
          Df[(size_t)blockIdx.z * strC + (size_t)(m + r) * ldc + n] = acc[rf][cf][r] * li;
        }
      }
    }
  }
}

// ---------------- host ----------------
extern "C" void kernel_launch(void* const* d_in, const int* in_sizes, int n_in,
                              void* d_out, int out_size, void* d_ws, size_t ws_size,
                              hipStream_t stream) {
  const float* X = (const float*)d_in[0];   // [4,4096,1024]
  const float* W = (const float*)d_in[1];   // [3072,1024]
  const float* b = (const float*)d_in[2];   // [3072]
  float* out = (float*)d_out;               // [4,4096,1024] fp32
  char* ws = (char*)d_ws;

  const size_t SB = (size_t)4096 * 4096 * 2;          // S bytes per batch
  const size_t QB = (size_t)4096 * 1024 * 2;
  const size_t WFB = (size_t)3072 * 1024 * 2;
  int NB = 1;
  if (ws_size >= 4 * SB + WFB + 12 * QB) NB = 4;
  else if (ws_size >= 2 * SB + WFB + 12 * QB) NB = 2;

  u16* S  = (u16*)(ws);
  u16* Xf = (u16*)(ws);                               // overlay; dead after QKV proj
  u16* Wf = (u16*)(ws + (size_t)NB * SB);
  u16* Qf = (u16*)(ws + (size_t)NB * SB + WFB);
  u16* Kf = (u16*)(ws + (size_t)NB * SB + WFB + 4 * QB);
  u16* Vt = (u16*)(ws + (size_t)NB * SB + WFB + 8 * QB);

  cast_f16_k<<<8192, 256, 0, stream>>>(X, Xf, 16777216 / 8);
  cast_f16_k<<<1536, 256, 0, stream>>>(W, Wf, 3145728 / 8);

  // QKV projection: M=16384, N=3072, K=1024
  gemm8p<1024, 2><<<dim3(64, 12, 1), 512, 0, stream>>>(
      Xf, Wf, b, Qf, Kf, Vt, nullptr, 0, 0, 0, 0);

  const size_t strQ = (size_t)4096 * 1024;
  const size_t strS = (size_t)4096 * 4096;
  const size_t strV = (size_t)1024 * 4096;
  for (int g = 0; g < 4; g += NB) {
    const u16* Qg = Qf + (size_t)g * strQ;
    const u16* Kg = Kf + (size_t)g * strQ;
    const u16* Vg = Vt + (size_t)g * strV;
    float* Og = out + (size_t)g * strQ;
    // S = exp(Q K^T / 32)  [4096x4096] x NB
    gemm8p<1024, 0><<<dim3(16, 16, NB), 512, 0, stream>>>(
        Qg, Kg, nullptr, S, nullptr, nullptr, nullptr, 4096, strQ, strQ, strS);
    // O = (S Vt^T) / rowsum(S)  [4096x1024] x NB  (rowsum fused via fdot2)
    gemm8p<4096, 1><<<dim3(16, 4, NB), 512, 0, stream>>>(
        S, Vg, nullptr, nullptr, nullptr, nullptr, Og, 1024, strS, strV, strQ);
  }
}

// Round 14
// 391.771 us; speedup vs baseline: 1.2370x; 1.0654x over previous
//
#include <hip/hip_runtime.h>
#include <hip/hip_bf16.h>

typedef unsigned short u16;
typedef _Float16 f16x8 __attribute__((ext_vector_type(8)));
typedef _Float16 f16x2 __attribute__((ext_vector_type(2)));
typedef float f32x4 __attribute__((ext_vector_type(4)));

#if __has_builtin(__builtin_amdgcn_exp2f)
#define EXP2F(x) __builtin_amdgcn_exp2f(x)
#else
#define EXP2F(x) exp2f(x)
#endif
// log2(e)/32 : p = exp2(acc * FA_C32) = exp(acc/32)
#define FA_C32 0.045084220027780106f

__device__ __forceinline__ f32x4 mfma16h(f16x8 a, f16x8 b, f32x4 c) {
  return __builtin_amdgcn_mfma_f32_16x16x32_f16(a, b, c, 0, 0, 0);
}
__device__ __forceinline__ unsigned pk2h(float a, float b) {
  union { _Float16 h[2]; unsigned u; } x;
  x.h[0] = (_Float16)a; x.h[1] = (_Float16)b;
  return x.u;
}
__device__ __forceinline__ u16 h1(float a) {
  union { _Float16 h; u16 u; } x; x.h = (_Float16)a; return x.u;
}

#if __has_builtin(__builtin_amdgcn_fdot2)
__device__ __forceinline__ float fdot2_(f16x2 a, f16x2 b, float c) {
  return __builtin_amdgcn_fdot2(a, b, c, false);
}
#else
__device__ __forceinline__ float fdot2_(f16x2 a, f16x2 b, float c) {
  return c + (float)a[0] * (float)b[0] + (float)a[1] * (float)b[1];
}
#endif

typedef __attribute__((address_space(1))) const unsigned int gas_u32;
typedef __attribute__((address_space(3))) unsigned int las_u32;
__device__ __forceinline__ void gl_lds16(const u16* g, u16* l) {
  __builtin_amdgcn_global_load_lds((gas_u32*)g, (las_u32*)l, 16, 0, 0);
}

// ---------------- cast fp32 -> f16, 8 elems/thread ----------------
__global__ __launch_bounds__(256) void cast_f16_k(const float* __restrict__ src,
                                                  u16* __restrict__ dst, int n8) {
  int i = blockIdx.x * 256 + threadIdx.x;
  if (i >= n8) return;
  const float4* s4 = (const float4*)src;
  float4 a = s4[i * 2], b = s4[i * 2 + 1];
  uint4 o;
  o.x = pk2h(a.x, a.y); o.y = pk2h(a.z, a.w);
  o.z = pk2h(b.x, b.y); o.w = pk2h(b.z, b.w);
  ((uint4*)dst)[i] = o;
}

// =================================================================
// Round-14: 3-phase GEMM (barrier count 8->6 per K-tile).
// BM=BN=256, BK=64, 8 waves (2Mx4N), acc 8x4, quarter-granularity staging.
// Per tile u (dbuf d=u&1), 3 phases:
//   phA: read a0(8),b0(4) | stage A q1,q3 of u+1 (dbuf d^1; a1(d^1) last read
//        phC of u-1, >=1 barrier earlier) | BAR lgkm0 | 16 MFMA (a0,b0)
//   phB: read b1(4)       | stage A q0,q2 of u+2 (a0(d) read phA)          
//        | BAR lgkm0 | 16 MFMA (a0,b1)
//   phC: read a1(8)       | stage B q0..q3 of u+2 (B(d) read phA/phB)
//        | BAR lgkm0 | 32 MFMA (a1,b1 + a1,b0) | vmcnt | BAR
// vmcnt trace (FIFO): at end of tile u outstanding =
//   [A02(u+1) 2, B(u+1) 4]  (from u-1)  +  [A13(u+1) 2, A02(u+2) 2, B(u+2) 4]
//   = 14; vmcnt(6) drains the 8 oldest = tile u+1 complete; keeps 6 = u+2's.
// Prologue: tile0 all 8 quarters + tile1 {A02,B} (6) -> vmcnt(6) drains tile0.
// Tails: u+2==NT -> vmcnt(0); last tile: nothing outstanding.
// WAR: every stage's target was last ds_read in a strictly earlier phase and
// serviced by that phase's lgkmcnt(0) BEFORE its closing barrier.
//   EPI=0: D0 f16 = exp(acc/32) (clamped)
//   EPI=1: Df f32 = acc / l_row  (l via fdot2 on A-fragments, wn==0 waves)
//   EPI=2: QKV scatter (Q,K row-major; V -> Vt[b][d][s])
// =================================================================
template <int K_, int EPI>
__global__ __launch_bounds__(512, 1) void gemm8p(
    const u16* __restrict__ A, const u16* __restrict__ B,
    const float* __restrict__ bias, u16* __restrict__ D0, u16* __restrict__ D1,
    u16* __restrict__ D2, float* __restrict__ Df, const int ldc,
    const size_t strA, const size_t strB, const size_t strC) {
  constexpr int NT = K_ / 64;
  static_assert(NT >= 4 && (NT % 2) == 0, "need even NT >= 4");
  __shared__ __align__(16) u16 As[2][2][128 * 64];   // [dbuf][M-half]
  __shared__ __align__(16) u16 Bs[2][2][128 * 64];   // [dbuf][N-half]
  __shared__ float lds_l[256];                       // EPI=1 row sums

  const int tid = threadIdx.x, lane = tid & 63, wid = tid >> 6;
  const int l15 = lane & 15, lhi = lane >> 4;
  const int m0 = blockIdx.x * 256, n0 = blockIdx.y * 256;
  const int wm = wid >> 2, wn = wid & 3;
  const u16* Ag = A + (size_t)blockIdx.z * strA;
  const u16* Bg = B + (size_t)blockIdx.z * strB;

  const int srow8 = lane >> 3;              // LDS row & 7 for this lane's 16B
  const int sblk = (lane & 7) ^ srow8;      // source block XOR (T2 both-sides)

// one 64-row quarter: 1 global_load_lds per wave (8 rows/wave)
#define STAGE_Q(BUF, G, GROW0, ST)                                        \
  gl_lds16((G) + (size_t)((GROW0) + wid * 8 + srow8) * K_ +               \
               (ST) * 64 + sblk * 8,                                      \
           (BUF) + (wid * 8) * 64)

#define BAR()                                                             \
  asm volatile("" ::: "memory");                                          \
  __builtin_amdgcn_s_barrier();                                           \
  asm volatile("" ::: "memory")

#define LGKM0()                                                           \
  asm volatile("s_waitcnt lgkmcnt(0)" ::: "memory");                      \
  __builtin_amdgcn_sched_barrier(0)

#define SB0() __builtin_amdgcn_sched_barrier(0)
#define VMC6() asm volatile("s_waitcnt vmcnt(6)" ::: "memory")
#define VMC0() asm volatile("s_waitcnt vmcnt(0)" ::: "memory")

#define RD_A(DST, PB, MH)                                                 \
  _Pragma("unroll") for (int mf = 0; mf < 4; ++mf)                        \
  _Pragma("unroll") for (int ks = 0; ks < 2; ++ks)                        \
    DST[mf][ks] = *(const f16x8*)((PB) + ((MH) * 64 + mf * 16 + l15) * 64 \
                                  + (((ks * 4 + lhi) ^ (l15 & 7)) * 8));

#define RD_B(DST, PB, BO, NH)                                             \
  _Pragma("unroll") for (int nf = 0; nf < 2; ++nf)                        \
  _Pragma("unroll") for (int ks = 0; ks < 2; ++ks)                        \
    DST[nf][ks] = *(const f16x8*)((PB) + ((BO) + (NH) * 32 + nf * 16 + l15) * 64 \
                                  + (((ks * 4 + lhi) ^ (l15 & 7)) * 8));

#define MM(AV, BV, MB, NB2)                                               \
  __builtin_amdgcn_s_setprio(1);                                          \
  _Pragma("unroll") for (int mf = 0; mf < 4; ++mf)                        \
  _Pragma("unroll") for (int nf = 0; nf < 2; ++nf)                        \
  _Pragma("unroll") for (int ks = 0; ks < 2; ++ks)                        \
    acc[(MB) * 4 + mf][(NB2) * 2 + nf] =                                  \
        mfma16h(AV[mf][ks], BV[nf][ks], acc[(MB) * 4 + mf][(NB2) * 2 + nf]); \
  __builtin_amdgcn_s_setprio(0);

// row-sum accumulate over an A fragment set (EPI=1, wn==0 waves only)
#define SUMA(FR, MH8)                                                     \
  if (EPI == 1 && wn == 0) {                                              \
    _Pragma("unroll") for (int mf = 0; mf < 4; ++mf)                      \
    _Pragma("unroll") for (int ks = 0; ks < 2; ++ks) {                    \
      const f16x2* _pr = (const f16x2*)&FR[mf][ks];                       \
      _Pragma("unroll") for (int j = 0; j < 4; ++j)                       \
        lsa[MH8][mf] = fdot2_(_pr[j], ones2, lsa[MH8][mf]);               \
    }                                                                     \
  }

  f32x4 acc[8][4];
#pragma unroll
  for (int i = 0; i < 8; ++i)
#pragma unroll
    for (int j = 0; j < 4; ++j) acc[i][j] = 0.f;

  float lsa[2][4];
#pragma unroll
  for (int i = 0; i < 2; ++i)
#pragma unroll
    for (int j = 0; j < 4; ++j) lsa[i][j] = 0.f;
  const f16x2 ones2 = {(_Float16)1.0f, (_Float16)1.0f};

  const int bofs = (wn & 1) * 64;

  // prologue: tile0 full (8 loads); tile1 A02+B (6 loads; A13(1) comes from
  // u=0's phA per schedule). vmcnt(6) drains tile0, keeps tile1's 6.
  STAGE_Q(&As[0][0][0],    Ag, m0,       0);
  STAGE_Q(&As[0][0][4096], Ag, m0 + 64,  0);
  STAGE_Q(&As[0][1][0],    Ag, m0 + 128, 0);
  STAGE_Q(&As[0][1][4096], Ag, m0 + 192, 0);
  STAGE_Q(&Bs[0][0][0],    Bg, n0,       0);
  STAGE_Q(&Bs[0][0][4096], Bg, n0 + 64,  0);
  STAGE_Q(&Bs[0][1][0],    Bg, n0 + 128, 0);
  STAGE_Q(&Bs[0][1][4096], Bg, n0 + 192, 0);
  STAGE_Q(&As[1][0][0],    Ag, m0,       1);
  STAGE_Q(&As[1][1][0],    Ag, m0 + 128, 1);
  STAGE_Q(&Bs[1][0][0],    Bg, n0,       1);
  STAGE_Q(&Bs[1][0][4096], Bg, n0 + 64,  1);
  STAGE_Q(&Bs[1][1][0],    Bg, n0 + 128, 1);
  STAGE_Q(&Bs[1][1][4096], Bg, n0 + 192, 1);
  VMC6();
  BAR();

#pragma unroll 2
  for (int u = 0; u < NT; ++u) {
    const int d = u & 1;
    const u16* Apb = &As[d][wm][0];
    const u16* Bpb = &Bs[d][wn >> 1][0];
    f16x8 a0[4][2], a1[4][2], b0[2][2], b1[2][2];

    // ---- phA: read a0,b0; stage A q1,q3 of u+1 (other dbuf) ----
    RD_A(a0, Apb, 0);
    RD_B(b0, Bpb, bofs, 0);
    if (u + 1 < NT) {
      STAGE_Q(&As[d ^ 1][0][4096], Ag, m0 + 64,  u + 1);
      STAGE_Q(&As[d ^ 1][1][4096], Ag, m0 + 192, u + 1);
    }
    BAR();
    LGKM0();
    MM(a0, b0, 0, 0);
    SUMA(a0, 0);
    SB0();
    BAR();

    // ---- phB: read b1; stage A q0,q2 of u+2 (same dbuf) ----
    RD_B(b1, Bpb, bofs, 1);
    if (u + 2 < NT) {
      STAGE_Q(&As[d][0][0], Ag, m0,       u + 2);
      STAGE_Q(&As[d][1][0], Ag, m0 + 128, u + 2);
    }
    BAR();
    LGKM0();
    MM(a0, b1, 0, 1);
    SB0();
    BAR();

    // ---- phC: read a1; stage B q0..q3 of u+2; 32 MFMA; boundary vmcnt ----
    RD_A(a1, Apb, 1);
    if (u + 2 < NT) {
      STAGE_Q(&Bs[d][0][0],    Bg, n0,       u + 2);
      STAGE_Q(&Bs[d][0][4096], Bg, n0 + 64,  u + 2);
      STAGE_Q(&Bs[d][1][0],    Bg, n0 + 128, u + 2);
      STAGE_Q(&Bs[d][1][4096], Bg, n0 + 192, u + 2);
    }
    BAR();
    LGKM0();
    MM(a1, b1, 1, 1);
    SUMA(a1, 1);
    MM(a1, b0, 1, 0);
    SB0();
    if (u + 2 < NT) { VMC6(); }
    else if (u + 2 == NT) { VMC0(); }
    BAR();
  }
#undef STAGE_Q
#undef BAR
#undef LGKM0
#undef SB0
#undef VMC6
#undef VMC0
#undef RD_A
#undef RD_B
#undef MM
#undef SUMA

  // ---------------- epilogues (wave tile rows wm*128, cols wn*64) ----------------
  if (EPI == 2) {
    float bv[4];
#pragma unroll
    for (int cf = 0; cf < 4; ++cf) bv[cf] = bias[n0 + wn * 64 + cf * 16 + l15];
    const int region = n0 >> 10;
    const int ncol0 = (n0 & 1023) + wn * 64;
    if (region < 2) {
      u16* dst = region ? D1 : D0;
#pragma unroll
      for (int rf = 0; rf < 8; ++rf) {
        const int m = m0 + wm * 128 + rf * 16 + lhi * 4;
#pragma unroll
        for (int r = 0; r < 4; ++r)
#pragma unroll
          for (int cf = 0; cf < 4; ++cf)
            dst[(size_t)(m + r) * 1024 + ncol0 + cf * 16 + l15] = h1(acc[rf][cf][r] + bv[cf]);
      }
    } else {
#pragma unroll
      for (int rf = 0; rf < 8; ++rf) {
        const int m = m0 + wm * 128 + rf * 16 + lhi * 4;
        const int bb = m >> 12, s = m & 4095;
#pragma unroll
        for (int cf = 0; cf < 4; ++cf) {
          const int dcol = ncol0 + cf * 16 + l15;
          uint2 v;
          v.x = pk2h(acc[rf][cf][0] + bv[cf], acc[rf][cf][1] + bv[cf]);
          v.y = pk2h(acc[rf][cf][2] + bv[cf], acc[rf][cf][3] + bv[cf]);
          *(uint2*)&D2[(size_t)(bb * 1024 + dcol) * 4096 + s] = v;
        }
      }
    }
  } else if (EPI == 0) {
    // p = exp(acc/32), f16-clamped, store (row sums computed in gemm3)
#pragma unroll
    for (int rf = 0; rf < 8; ++rf) {
      const int m = m0 + wm * 128 + rf * 16 + lhi * 4;
#pragma unroll
      for (int r = 0; r < 4; ++r)
#pragma unroll
        for (int cf = 0; cf < 4; ++cf) {
          const int n = n0 + wn * 64 + cf * 16 + l15;
          float p = fminf(EXP2F(acc[rf][cf][r] * FA_C32), 60000.f);
          D0[(size_t)blockIdx.z * strC + (size_t)(m + r) * ldc + n] = h1(p);
        }
    }
  } else {
    // publish row sums (lanes hold rows at l15; C rows live at lhi*4+r)
    if (wn == 0) {
#pragma unroll
      for (int mh = 0; mh < 2; ++mh)
#pragma unroll
        for (int mf = 0; mf < 4; ++mf) {
          float s = lsa[mh][mf];
          s += __shfl_xor(s, 16, 64);
          s += __shfl_xor(s, 32, 64);
          if (lhi == 0) lds_l[wm * 128 + mh * 64 + mf * 16 + l15] = s;
        }
    }
    __syncthreads();
#pragma unroll
    for (int rf = 0; rf < 8; ++rf) {
      const int m = m0 + wm * 128 + rf * 16 + lhi * 4;
#pragma unroll
      for (int r = 0; r < 4; ++r) {
        const float li = 1.0f / lds_l[wm * 128 + rf * 16 + lhi * 4 + r];
#pragma unroll
        for (int cf = 0; cf < 4; ++cf) {
          const int n = n0 + wn * 64 + cf * 16 + l15;
          Df[(size_t)blockIdx.z * strC + (size_t)(m + r) * ldc + n] = acc[rf][cf][r] * li;
        }
      }
    }
  }
}

// ---------------- host ----------------
extern "C" void kernel_launch(void* const* d_in, const int* in_sizes, int n_in,
                              void* d_out, int out_size, void* d_ws, size_t ws_size,
                              hipStream_t stream) {
  const float* X = (const float*)d_in[0];   // [4,4096,1024]
  const float* W = (const float*)d_in[1];   // [3072,1024]
  const float* b = (const float*)d_in[2];   // [3072]
  float* out = (float*)d_out;               // [4,4096,1024] fp32
  char* ws = (char*)d_ws;

  const size_t SB = (size_t)4096 * 4096 * 2;          // S bytes per batch
  const size_t QB = (size_t)4096 * 1024 * 2;
  const size_t WFB = (size_t)3072 * 1024 * 2;
  int NB = 1;
  if (ws_size >= 4 * SB + WFB + 12 * QB) NB = 4;
  else if (ws_size >= 2 * SB + WFB + 12 * QB) NB = 2;

  u16* S  = (u16*)(ws);
  u16* Xf = (u16*)(ws);                               // overlay; dead after QKV proj
  u16* Wf = (u16*)(ws + (size_t)NB * SB);
  u16* Qf = (u16*)(ws + (size_t)NB * SB + WFB);
  u16* Kf = (u16*)(ws + (size_t)NB * SB + WFB + 4 * QB);
  u16* Vt = (u16*)(ws + (size_t)NB * SB + WFB + 8 * QB);

  cast_f16_k<<<8192, 256, 0, stream>>>(X, Xf, 16777216 / 8);
  cast_f16_k<<<1536, 256, 0, stream>>>(W, Wf, 3145728 / 8);

  // QKV projection: M=16384, N=3072, K=1024
  gemm8p<1024, 2><<<dim3(64, 12, 1), 512, 0, stream>>>(
      Xf, Wf, b, Qf, Kf, Vt, nullptr, 0, 0, 0, 0);

  const size_t strQ = (size_t)4096 * 1024;
  const size_t strS = (size_t)4096 * 4096;
  const size_t strV = (size_t)1024 * 4096;
  for (int g = 0; g < 4; g += NB) {
    const u16* Qg = Qf + (size_t)g * strQ;
    const u16* Kg = Kf + (size_t)g * strQ;
    const u16* Vg = Vt + (size_t)g * strV;
    float* Og = out + (size_t)g * strQ;
    // S = exp(Q K^T / 32)  [4096x4096] x NB
    gemm8p<1024, 0><<<dim3(16, 16, NB), 512, 0, stream>>>(
        Qg, Kg, nullptr, S, nullptr, nullptr, nullptr, 4096, strQ, strQ, strS);
    // O = (S Vt^T) / rowsum(S)  [4096x1024] x NB  (rowsum fused via fdot2)
    gemm8p<4096, 1><<<dim3(16, 4, NB), 512, 0, stream>>>(
        S, Vg, nullptr, nullptr, nullptr, nullptr, Og, 1024, strS, strV, strQ);
  }
}